// Round 12
// baseline (117.700 us; speedup 1.0000x reference)
//
#include <hip/hip_runtime.h>
#include <stdint.h>

typedef unsigned short u16;
typedef __attribute__((ext_vector_type(8))) short short8;
typedef __attribute__((ext_vector_type(4))) short short4v;
typedef __attribute__((ext_vector_type(4))) float f32x4;

#define NB    16
#define DIM   256
#define NTOK  1024

__device__ __forceinline__ u16 f2b(float f) {
    union { float f; uint32_t u; } v; v.f = f;
    uint32_t u = v.u;
    u += 0x7fffu + ((u >> 16) & 1u);
    return (u16)(u >> 16);
}
__device__ __forceinline__ uint32_t pack2(float a, float b) {
    return (uint32_t)f2b(a) | ((uint32_t)f2b(b) << 16);
}
__device__ __forceinline__ f32x4 mfma16(short8 a, short8 b, f32x4 c) {
    return __builtin_amdgcn_mfma_f32_16x16x32_bf16(a, b, c, 0, 0, 0);
}
// K=16 MFMA, B-frag in-lane (k=4*hi+j) — layout proven in round 8 (passed).
__device__ __forceinline__ f32x4 mfma16k16(short4v a, short4v b, f32x4 c) {
    asm volatile("v_mfma_f32_16x16x16_bf16 %0, %1, %2, %0"
                 : "+v"(c) : "v"(a), "v"(b));
    return c;
}
__device__ __forceinline__ short8 ld8(const u16* p) {
    return *reinterpret_cast<const short8*>(p);
}
__device__ __forceinline__ short4v ld4(const u16* p) {
    return *reinterpret_cast<const short4v*>(p);
}
__device__ __forceinline__ void gl_lds(const u16* g, u16* l) {
    __builtin_amdgcn_global_load_lds((const __attribute__((address_space(1))) void*)g,
                                     (__attribute__((address_space(3))) void*)l, 16, 0, 0);
}

// ---------------- Kernel 1: pack x -> xbf + nodes; blocks >=1024 convert weights.
__global__ __launch_bounds__(256) void pack_kernel(const float* __restrict__ x,
                                                   u16* __restrict__ xbf,
                                                   u16* __restrict__ nodes,
                                                   const float* __restrict__ pw,
                                                   const float* __restrict__ w1,
                                                   const float* __restrict__ w2,
                                                   u16* __restrict__ wbf) {
    __shared__ float tile[64][67];
    int tid = threadIdx.x;
    int blk = blockIdx.x;
    if (blk >= 1024) {               // weight conversion: 96 blocks x 2048 elems
        int e = (blk - 1024) * 2048 + tid * 8;
        const float* s; int off;
        if (e < 65536)       { s = pw; off = e; }
        else if (e < 131072) { s = w1; off = e - 65536; }
        else                 { s = w2; off = e - 131072; }
        float4 f0 = *reinterpret_cast<const float4*>(s + off);
        float4 f1 = *reinterpret_cast<const float4*>(s + off + 4);
        ushort4 a, bb;
        a.x = f2b(f0.x); a.y = f2b(f0.y); a.z = f2b(f0.z); a.w = f2b(f0.w);
        bb.x = f2b(f1.x); bb.y = f2b(f1.y); bb.z = f2b(f1.z); bb.w = f2b(f1.w);
        *reinterpret_cast<ushort4*>(wbf + e)     = a;
        *reinterpret_cast<ushort4*>(wbf + e + 4) = bb;
        return;
    }
    int b  = blk >> 6;
    int t  = blk & 63;
    int c0 = (t >> 4) << 6;
    int n0 = (t & 15) << 6;
    const float* xb = x + (size_t)b * (DIM * NTOK);
    u16* xbb = xbf + (size_t)b * (DIM * NTOK);
#pragma unroll
    for (int i = 0; i < 4; i++) {
        int idx = i * 256 + tid;
        int cl = idx >> 4, nq = idx & 15;
        float4 f = *reinterpret_cast<const float4*>(xb + (size_t)(c0 + cl) * NTOK + n0 + nq * 4);
        tile[cl][nq * 4 + 0] = f.x;
        tile[cl][nq * 4 + 1] = f.y;
        tile[cl][nq * 4 + 2] = f.z;
        tile[cl][nq * 4 + 3] = f.w;
        ushort4 s;
        s.x = f2b(f.x); s.y = f2b(f.y); s.z = f2b(f.z); s.w = f2b(f.w);
        *reinterpret_cast<ushort4*>(xbb + (size_t)(c0 + cl) * NTOK + n0 + nq * 4) = s;
    }
    __syncthreads();
#pragma unroll
    for (int i = 0; i < 4; i++) {
        int idx = i * 256 + tid;
        int nl = idx >> 4, cq = idx & 15;
        ushort4 s;
        s.x = f2b(tile[cq * 4 + 0][nl]);
        s.y = f2b(tile[cq * 4 + 1][nl]);
        s.z = f2b(tile[cq * 4 + 2][nl]);
        s.w = f2b(tile[cq * 4 + 3][nl]);
        *reinterpret_cast<ushort4*>(nodes + (size_t)(b * NTOK + n0 + nl) * DIM + c0 + cq * 4) = s;
    }
}

// ---------------- Kernel 2: q = nodes @ proj_w^T + proj_b. 4-way column split.
__global__ __launch_bounds__(256) void proj_kernel(const u16* __restrict__ nodes,
                                                   const u16* __restrict__ wbf,
                                                   const float* __restrict__ pb,
                                                   u16* __restrict__ qb) {
    int lane = threadIdx.x & 63;
    int w = threadIdx.x >> 6;
    int lo = lane & 15, hi = lane >> 4;
    int ch = blockIdx.x & 3;
    int row0 = (blockIdx.x >> 2) * 64 + w * 16;
    const u16* arow = nodes + (size_t)(row0 + lo) * DIM + hi * 8;
    f32x4 acc[4];
#pragma unroll
    for (int i = 0; i < 4; i++) acc[i] = (f32x4){0.f, 0.f, 0.f, 0.f};
#pragma unroll
    for (int t = 0; t < 8; t++) {
        short8 a = ld8(arow + t * 32);
#pragma unroll
        for (int nf = 0; nf < 4; nf++) {
            short8 bfr = ld8(wbf + ((ch * 4 + nf) * 16 + lo) * DIM + t * 32 + hi * 8);
            acc[nf] = mfma16(a, bfr, acc[nf]);
        }
    }
#pragma unroll
    for (int nf = 0; nf < 4; nf++) {
        int col = (ch * 4 + nf) * 16 + lo;
        float bias = pb[col];
#pragma unroll
        for (int r = 0; r < 4; r++) {
            int row = row0 + hi * 4 + r;
            qb[(size_t)row * DIM + col] = f2b(acc[nf][r] + bias);
        }
    }
}

// ---------------- Kernel 3: fused attention + FFN. 512 blocks x 256 thr -> 2 blocks/CU.
// Block = 32 q rows x 1 batch; 4 waves = 2 qsel(16 rows) x 2 kvh(512 kv each).
// KV in 16-row tiles (dbuf, 64 KB total). PV uses K=16 MFMA with in-lane P
// (no shuffles). Softmax with FIXED offset (exact math, no online max).
__global__ __launch_bounds__(256, 2) void attn_ffn_kernel(const u16* __restrict__ qb,
                                                          const u16* __restrict__ xbf,
                                                          const u16* __restrict__ wbf,
                                                          const float* __restrict__ b1,
                                                          const float* __restrict__ b2,
                                                          const float* __restrict__ x,
                                                          float* __restrict__ out) {
    __shared__ u16 kls[2][2][4096];   // [stream][buf][16 rows x 256 ch]  32 KB
    __shared__ u16 vls[2][2][4096];   // [stream][buf][256 ch x 16 kv]    32 KB
    __shared__ float ellX[4][16];

    int lane = threadIdx.x & 63;
    int w = threadIdx.x >> 6;            // 0..3
    int qsel = w >> 1, kvh = w & 1;
    int lo = lane & 15, hi = lane >> 4;
    int b  = blockIdx.x & 15;            // same-batch blocks share an XCD (blk%8=b%8)
    int qt = blockIdx.x >> 4;            // 0..31
    int q0 = qt * 32 + qsel * 16;
    const u16* qbb = qb  + (size_t)b * (NTOK * DIM);
    const u16* xbb = xbf + (size_t)b * (DIM * NTOK);
    const u16* w1b = wbf + 65536;
    const u16* w2b = wbf + 131072;

    // staging: stream kvh staged by its 2 waves; each wave 4 K-instr + 4 V-instr
    int kOff[4], vOff[4], kDst[4], vDst[4];
#pragma unroll
    for (int i = 0; i < 4; i++) {
        int kr = qsel * 8 + i * 2 + (lane >> 5);             // K row in 16-row tile
        kOff[i] = kr * DIM + ((lane & 31) ^ (kr & 7)) * 8;   // pre-swizzled source
        kDst[i] = (qsel * 8 + i * 2) * 256;
        int vc = qsel * 128 + i * 32 + (lane >> 1);          // V channel (linear)
        vOff[i] = vc * NTOK + (lane & 1) * 8;
        vDst[i] = (qsel * 128 + i * 32) * 16;
    }
    int kvbeg = kvh * 512;

    short8 bq[8];
#pragma unroll
    for (int t = 0; t < 8; t++)
        bq[t] = ld8(qbb + (size_t)(q0 + lo) * DIM + t * 32 + hi * 8);

    f32x4 acc[16];
#pragma unroll
    for (int i = 0; i < 16; i++) acc[i] = (f32x4){0.f, 0.f, 0.f, 0.f};
    float ellp = 0.f;
    const float C1 = 0.0625f * 1.44269504f;   // /16 and log2(e) folded
    const float OFF = 12.0f;                  // fixed exp2-domain offset (|s*C1| << 12)

    // prologue: stage tile 0
#pragma unroll
    for (int i = 0; i < 4; i++) {
        gl_lds(qbb + kvbeg * DIM + kOff[i], &kls[kvh][0][kDst[i]]);
        gl_lds(xbb + kvbeg       + vOff[i], &vls[kvh][0][vDst[i]]);
    }
    __syncthreads();

    for (int tt = 0; tt < 32; tt++) {
        int buf = tt & 1;
        if (tt < 31) {
            int base = kvbeg + (tt + 1) * 16;
#pragma unroll
            for (int i = 0; i < 4; i++) {
                gl_lds(qbb + base * DIM + kOff[i], &kls[kvh][buf ^ 1][kDst[i]]);
                gl_lds(xbb + base       + vOff[i], &vls[kvh][buf ^ 1][vDst[i]]);
            }
        }
        const u16* kb = &kls[kvh][buf][0];
        const u16* vb = &vls[kvh][buf][0];

        // QK^T: one 16-row kv frag, two interleaved 4-deep chains
        f32x4 sa = (f32x4){0.f, 0.f, 0.f, 0.f};
        f32x4 sb = (f32x4){0.f, 0.f, 0.f, 0.f};
        __builtin_amdgcn_s_setprio(1);
#pragma unroll
        for (int t = 0; t < 8; t += 2) {
            int sl0 = ((t * 4 + hi) ^ (lo & 7)) * 8;
            int sl1 = (((t + 1) * 4 + hi) ^ (lo & 7)) * 8;
            sa = mfma16(ld8(kb + lo * 256 + sl0), bq[t],     sa);
            sb = mfma16(ld8(kb + lo * 256 + sl1), bq[t + 1], sb);
        }
        __builtin_amdgcn_s_setprio(0);

        // softmax numerator, fixed offset; ell accumulated per-lane
        float p0 = exp2f((sa[0] + sb[0]) * C1 - OFF);
        float p1 = exp2f((sa[1] + sb[1]) * C1 - OFF);
        float p2 = exp2f((sa[2] + sb[2]) * C1 - OFF);
        float p3 = exp2f((sa[3] + sb[3]) * C1 - OFF);
        ellp += (p0 + p1) + (p2 + p3);

        // in-lane K=16 B-frag: P[q=lo][kv=4*hi+j]
        union { uint32_t u[2]; short4v v; } pa;
        pa.u[0] = pack2(p0, p1);
        pa.u[1] = pack2(p2, p3);

        // PV: 16 ch frags, one K=16 step each (no shuffles)
        __builtin_amdgcn_s_setprio(1);
#pragma unroll
        for (int mf = 0; mf < 16; mf++) {
            short4v vf = ld4(vb + (mf * 16 + lo) * 16 + hi * 4);
            acc[mf] = mfma16k16(vf, pa.v, acc[mf]);
        }
        __builtin_amdgcn_s_setprio(0);
        __syncthreads();
    }

    asm volatile("s_nop 7\n\ts_nop 7" ::: "memory");   // MFMA->VALU guard

    // ---- combine across kv-halves (plain adds; shared fixed offset) ----
    float e = ellp;
    e += __shfl_xor(e, 16);
    e += __shfl_xor(e, 32);
    if (lane < 16) ellX[w][lane] = e;

    char* pbase = (char*)kls;   // 32 KB giveaway scratch (4 waves x 8 KB)
    if (kvh == 0) {
#pragma unroll
        for (int j = 0; j < 8; j++) {
            int byt = w * 8192 + lo * 512 + ((j * 64 + hi * 16) ^ ((lo & 7) << 4));
            *reinterpret_cast<f32x4*>(pbase + byt) = acc[8 + j];
        }
    } else {
#pragma unroll
        for (int j = 0; j < 8; j++) {
            int byt = w * 8192 + lo * 512 + ((j * 64 + hi * 16) ^ ((lo & 7) << 4));
            *reinterpret_cast<f32x4*>(pbase + byt) = acc[j];
        }
    }
    __syncthreads();
    float rinv = 1.f / (e + ellX[w ^ 1][lo]);
    char* abase = (char*)vls;   // agg tile [32 rows][256 ch] bf16, 16B-granule ^(row&7)
    int arow = qsel * 16 + lo;
    if (kvh == 0) {
#pragma unroll
        for (int j = 0; j < 8; j++) {
            int byt = (w ^ 1) * 8192 + lo * 512 + ((j * 64 + hi * 16) ^ ((lo & 7) << 4));
            f32x4 o = *reinterpret_cast<const f32x4*>(pbase + byt);
            uint32_t lo32 = pack2((acc[j][0] + o[0]) * rinv, (acc[j][1] + o[1]) * rinv);
            uint32_t hi32 = pack2((acc[j][2] + o[2]) * rinv, (acc[j][3] + o[3]) * rinv);
            int slot = j * 2 + (hi >> 1);
            int byteA = arow * 512 + ((slot ^ (lo & 7)) * 16) + (hi & 1) * 8;
            *reinterpret_cast<uint32_t*>(abase + byteA)     = lo32;
            *reinterpret_cast<uint32_t*>(abase + byteA + 4) = hi32;
        }
    } else {
#pragma unroll
        for (int j = 0; j < 8; j++) {
            int byt = (w ^ 1) * 8192 + lo * 512 + ((j * 64 + hi * 16) ^ ((lo & 7) << 4));
            f32x4 o = *reinterpret_cast<const f32x4*>(pbase + byt);
            uint32_t lo32 = pack2((acc[8 + j][0] + o[0]) * rinv, (acc[8 + j][1] + o[1]) * rinv);
            uint32_t hi32 = pack2((acc[8 + j][2] + o[2]) * rinv, (acc[8 + j][3] + o[3]) * rinv);
            int slot = 16 + j * 2 + (hi >> 1);
            int byteA = arow * 512 + ((slot ^ (lo & 7)) * 16) + (hi & 1) * 8;
            *reinterpret_cast<uint32_t*>(abase + byteA)     = lo32;
            *reinterpret_cast<uint32_t*>(abase + byteA + 4) = hi32;
        }
    }
    __syncthreads();

    // ---- FFN on this block's 32 rows: 4 waves = 2 rowtiles(16) x 2 colhalves(128)
    int rh = w & 1, chh = w >> 1;
    f32x4 f1[8];
#pragma unroll
    for (int i = 0; i < 8; i++) f1[i] = (f32x4){0.f, 0.f, 0.f, 0.f};
#pragma unroll
    for (int t = 0; t < 8; t++) {
        int g = ((t * 4 + hi) ^ (lo & 7)) * 16;
        short8 a = *reinterpret_cast<const short8*>(abase + (rh * 16 + lo) * 512 + g);
#pragma unroll
        for (int nf = 0; nf < 8; nf++) {
            short8 bfr = ld8(w1b + ((chh * 8 + nf) * 16 + lo) * DIM + t * 32 + hi * 8);
            f1[nf] = mfma16(a, bfr, f1[nf]);
        }
    }
    u16* hl = (u16*)kls;   // [32][264]
#pragma unroll
    for (int nf = 0; nf < 8; nf++) {
        int f = (chh * 8 + nf) * 16 + lo;
        float bias = b1[f];
#pragma unroll
        for (int r = 0; r < 4; r++) {
            float v = f1[nf][r] + bias;
            float g = 0.5f * v * (1.f + erff(v * 0.70710678f));
            hl[(rh * 16 + hi * 4 + r) * 264 + f] = f2b(g);
        }
    }
    __syncthreads();

    f32x4 f2[8];
#pragma unroll
    for (int i = 0; i < 8; i++) f2[i] = (f32x4){0.f, 0.f, 0.f, 0.f};
#pragma unroll
    for (int t = 0; t < 8; t++) {
        short8 bh = ld8(hl + (rh * 16 + lo) * 264 + t * 32 + hi * 8);
#pragma unroll
        for (int mf = 0; mf < 8; mf++) {
            short8 a2 = ld8(w2b + ((chh * 8 + mf) * 16 + lo) * DIM + t * 32 + hi * 8);
            f2[mf] = mfma16(a2, bh, f2[mf]);
        }
    }
    int n = qt * 32 + rh * 16 + lo;
#pragma unroll
    for (int mf = 0; mf < 8; mf++) {
#pragma unroll
        for (int r = 0; r < 4; r++) {
            int co = (chh * 8 + mf) * 16 + hi * 4 + r;
            size_t addr = (size_t)b * (DIM * NTOK) + (size_t)co * NTOK + n;
            out[addr] = f2[mf][r] + b2[co] + x[addr];
        }
    }
}

extern "C" void kernel_launch(void* const* d_in, const int* in_sizes, int n_in,
                              void* d_out, int out_size, void* d_ws, size_t ws_size,
                              hipStream_t stream) {
    const float* x      = (const float*)d_in[0];
    const float* proj_w = (const float*)d_in[1];
    const float* proj_b = (const float*)d_in[2];
    const float* w1     = (const float*)d_in[3];
    const float* b1     = (const float*)d_in[4];
    const float* w2     = (const float*)d_in[5];
    const float* b2     = (const float*)d_in[6];
    float* out = (float*)d_out;

    u16* xbf   = (u16*)d_ws;
    u16* nodes = xbf   + 4194304;
    u16* qb    = nodes + 4194304;
    u16* wbf   = qb    + 4194304;

    pack_kernel    <<<1120, 256, 0, stream>>>(x, xbf, nodes, proj_w, w1, w2, wbf);
    proj_kernel    <<<1024, 256, 0, stream>>>(nodes, wbf, proj_b, qb);
    attn_ffn_kernel<<<512,  256, 0, stream>>>(qb, xbf, wbf, b1, b2, x, out);
}